// Round 13
// baseline (296.008 us; speedup 1.0000x reference)
//
#include <hip/hip_runtime.h>

// TSP_GNN: 2x GCNConv(edge-weighted, self-loops) + FC + row softmax.
// N=8192 nodes, E=262144 edges, H=64.
// R10: X pre-cast to bf16 via sequential stream (k_xcast -> d_out scratch);
// gemm1 = plain-bf16 MFMA (no hi/lo split), 32KB LDS dbuf, 4 blocks/CU,
// counted vmcnt(4) across raw barriers. B = w1hi only (R6 verified pack).

#define NN 8192
#define NE 262144
#define HD 64
#define KCH 1024       // K-chunk per gemm1 block
#define NKC 8          // number of K-chunks
#define NTS (KCH/64)   // 16 k-steps per block

typedef float f32x4 __attribute__((ext_vector_type(4)));
typedef short v8s   __attribute__((ext_vector_type(8)));
typedef unsigned short ushort_t;

__device__ __forceinline__ unsigned short bf16_rne(float f){
  union { float f; unsigned u; } v; v.f = f;
  unsigned r = v.u + 0x7fffu + ((v.u >> 16) & 1u);
  return (unsigned short)(r >> 16);
}
__device__ __forceinline__ float bf16_f32(unsigned short h){
  union { unsigned u; float f; } v; v.u = ((unsigned)h) << 16;
  return v.f;
}
__device__ __forceinline__ f32x4 mfma16(v8s a, v8s b, f32x4 c){
  return __builtin_amdgcn_mfma_f32_16x16x32_bf16(a, b, c, 0, 0, 0);
}
// async global->LDS, 16B per lane; lds base wave-uniform, global addr per-lane.
__device__ __forceinline__ void gload16(const void* g, void* l){
  __builtin_amdgcn_global_load_lds(
      (const __attribute__((address_space(1))) unsigned int*)g,
      (__attribute__((address_space(3))) unsigned int*)l, 16, 0, 0);
}

// ---------------- X -> bf16 sequential stream ----------------
// 67108864 elems = 32768 blocks x 256 thr x 8 elems. Fully coalesced.
__global__ __launch_bounds__(256) void k_xcast(const float* __restrict__ X,
                                               ushort_t* __restrict__ xb){
  size_t i = ((size_t)blockIdx.x*256 + threadIdx.x)*8;
  f32x4 a = *(const f32x4*)(X + i);
  f32x4 b = *(const f32x4*)(X + i + 4);
  v8s o;
  #pragma unroll
  for (int j=0;j<4;++j){
    o[j]   = (short)bf16_rne(a[j]);
    o[4+j] = (short)bf16_rne(b[j]);
  }
  *(v8s*)(xb + i) = o;
}

// ---------------- prep: init + pack W1 (hi, chunk-swizzled) + pack fcW ----
// W1 frag layout idx = ((kb*4+nt)*16+c)*32+kk, stored at sidx = ((chunk^(c&7))<<3)|e.
__global__ void k_prep0(const float* __restrict__ W1, const float* __restrict__ fcW,
                        ushort_t* w1hi, ushort_t* fcwp,
                        float* deg, int* cnt, int* wcnt, float* S){
  int idx = blockIdx.x*blockDim.x + threadIdx.x;   // 0..524287
  if (idx < NN){ deg[idx]=1.0f; cnt[idx]=0; wcnt[idx]=0; S[idx]=0.0f; }
  {
    int kk = idx & 31, c = (idx>>5)&15, nt = (idx>>9)&3, kb = idx>>11;
    int k = kb*32 + kk, col = nt*16 + c;
    float w = W1[(size_t)k*HD + col];
    int chunk = idx >> 3, e = idx & 7;
    int sidx = ((chunk ^ (c & 7)) << 3) | e;
    w1hi[sidx] = bf16_rne(w);
  }
  {
    int kk = idx & 31, c = (idx>>5)&15, cblk = (idx>>9)&511, kb = idx>>18;
    int k = kb*32 + kk, col = cblk*16 + c;
    fcwp[idx] = bf16_rne(fcW[(size_t)k*NN + col]);
  }
}

__global__ void k_deg_cnt(const int* ei, const float* ew, float* deg, int* cnt){
  int e = blockIdx.x*blockDim.x + threadIdx.x;
  if (e < NE){
    int d = ei[NE + e];
    atomicAdd(&deg[d], ew[e]);
    atomicAdd(&cnt[d], 1);
  }
}

__global__ void k_scan(const int* cnt, const float* deg, int* rowptr, float* dinv){
  __shared__ int part[256];
  int t = threadIdx.x;
  int loc[32]; int s = 0;
  #pragma unroll
  for (int j=0;j<32;++j){ loc[j] = cnt[t*32+j]; s += loc[j]; }
  part[t] = s; __syncthreads();
  for (int off=1; off<256; off<<=1){
    int v = (t >= off) ? part[t-off] : 0;
    __syncthreads();
    part[t] += v;
    __syncthreads();
  }
  int run = part[t] - s;
  #pragma unroll
  for (int j=0;j<32;++j){ rowptr[t*32+j] = run; run += loc[j]; }
  if (t == 255) rowptr[NN] = run;
  #pragma unroll
  for (int j=0;j<32;++j) dinv[t*32+j] = 1.0f / sqrtf(deg[t*32+j]);
}

__global__ void k_fill(const int* ei, const float* ew, const float* dinv,
                       const int* rowptr, int* wcnt, int* csr_src, float* csr_nrm){
  int e = blockIdx.x*blockDim.x + threadIdx.x;
  if (e < NE){
    int s = ei[e], d = ei[NE+e];
    int slot = rowptr[d] + atomicAdd(&wcnt[d], 1);
    csr_src[slot] = s;
    csr_nrm[slot] = dinv[s] * ew[e] * dinv[d];
  }
}

// ---------------- GEMM1: xw1p[kc] = Xbf[:, kc] @ W1hi[kc, :] ----------------
// 4 waves x 16 rows = 64 rows/block; k-step 64 (2 MFMA k-groups).
// A: LDS [64 rows][128 B], chunk-XOR keyed by row (pre-swizzled source).
// B: two 4KB kb-slices per step, R6 verified pack/read pair.
// Counted s_waitcnt vmcnt(4) across raw s_barrier (prefetch survives barrier).
__global__ __launch_bounds__(256, 4) void k_gemm1(const ushort_t* __restrict__ Xb,
                                                  const ushort_t* __restrict__ w1hi,
                                                  float* __restrict__ xw1p){
  __shared__ __align__(16) char sA[2][8192];
  __shared__ __align__(16) char sB[2][8192];
  int lane = threadIdx.x & 63, w = threadIdx.x >> 6;
  int r = lane & 15, seg = lane >> 4;
  int c8 = lane & 7, r8 = lane >> 3;          // staging roles: chunk, row-in-8
  int row0 = blockIdx.x*64, kb0 = blockIdx.y*KCH;

  const char* Xc  = (const char*)Xb;
  const char* w1c = (const char*)w1hi;
  // A source: instr i covers local rows w*16+i*8 .. +7 (lane row r8, chunk c8^r8)
  size_t asrc[2];
  #pragma unroll
  for (int i=0;i<2;++i){
    int rl = w*16 + i*8 + r8;
    asrc[i] = (size_t)(row0 + rl)*(NN*2) + (size_t)kb0*2 + (size_t)((c8 ^ r8)*16);
  }

  // ds_read addresses
  int aoff[2];
  #pragma unroll
  for (int ks=0; ks<2; ++ks)
    aoff[ks] = (w*16 + r)*128 + (((ks*4 + seg) ^ (r & 7)) << 4);
  int bc[4];
  #pragma unroll
  for (int nt=0; nt<4; ++nt)
    bc[nt] = ((nt*64 + r*4 + seg) ^ (r & 7)) << 4;

  f32x4 z = {0.f,0.f,0.f,0.f};
  f32x4 acc[4] = {z,z,z,z};

  auto STAGE = [&](int t, int b){
    char* aD = (char*)sA[b] + w*2048;
    gload16(Xc + asrc[0] + (size_t)t*128, aD);
    gload16(Xc + asrc[1] + (size_t)t*128, aD + 1024);
    size_t sBo = ((size_t)(kb0 >> 5) + 2*t)*4096 + w*1024 + lane*16;
    gload16(w1c + sBo,        (char*)sB[b] + w*1024);
    gload16(w1c + sBo + 4096, (char*)sB[b] + 4096 + w*1024);
  };

  STAGE(0, 0);

  for (int t = 0; t < NTS; ++t){
    int cur = t & 1;
    if (t + 1 < NTS){
      STAGE(t+1, cur^1);                                  // 8 outstanding
      asm volatile("s_waitcnt vmcnt(4)" ::: "memory");    // step t landed
    } else {
      asm volatile("s_waitcnt vmcnt(0)" ::: "memory");
    }
    __builtin_amdgcn_s_barrier();
    __builtin_amdgcn_sched_barrier(0);
    #pragma unroll
    for (int ks=0; ks<2; ++ks){
      v8s a = *(const v8s*)(&sA[cur][aoff[ks]]);
      #pragma unroll
      for (int nt=0; nt<4; ++nt){
        v8s b = *(const v8s*)(&sB[cur][ks*4096 + bc[nt]]);
        acc[nt] = mfma16(a, b, acc[nt]);
      }
    }
    __builtin_amdgcn_sched_barrier(0);
    __builtin_amdgcn_s_barrier();
  }

  // D layout: row-within-16 = 4*seg+j, col = nt*16+r
  float* o = xw1p + (size_t)blockIdx.y*(NN*HD) + (size_t)(row0 + w*16)*HD;
  #pragma unroll
  for (int nt=0; nt<4; ++nt)
    #pragma unroll
    for (int j=0;j<4;++j)
      o[(4*seg + j)*HD + nt*16 + r] = acc[nt][j];
}

// reduce NKC partial planes -> xw1
__global__ __launch_bounds__(256) void k_red(const float* __restrict__ xw1p,
                                             float* __restrict__ xw1){
  int i = blockIdx.x*blockDim.x + threadIdx.x;   // over NN*HD/4
  f32x4 s = {0.f,0.f,0.f,0.f};
  #pragma unroll
  for (int c=0;c<NKC;++c){
    f32x4 v = *(const f32x4*)(xw1p + (size_t)c*NN*HD + (size_t)i*4);
    s[0]+=v[0]; s[1]+=v[1]; s[2]+=v[2]; s[3]+=v[3];
  }
  *(f32x4*)(xw1 + (size_t)i*4) = s;
}

// ---------------- agg1 + conv2 fused ----------------
__global__ __launch_bounds__(256) void k_agg1c(const float* __restrict__ xin,
                                               const float* __restrict__ b1,
                                               const float* __restrict__ W2,
                                               const float* __restrict__ dinv,
                                               const int* __restrict__ rowptr,
                                               const int* __restrict__ csr_src,
                                               const float* __restrict__ csr_nrm,
                                               float* __restrict__ x2w){
  __shared__ float W2s[64*64];
  __shared__ float rows[4][64];
  int lane = threadIdx.x & 63, w = threadIdx.x >> 6;
  for (int o = threadIdx.x; o < 64*64; o += 256) W2s[o] = W2[o];
  __syncthreads();

  int i = blockIdx.x*4 + w;
  float di = dinv[i];
  float acc = di*di * xin[(size_t)i*HD + lane];
  int e = rowptr[i], e1 = rowptr[i+1];
  for (; e + 1 < e1; e += 2){
    int s0 = csr_src[e], s1 = csr_src[e+1];
    float n0 = csr_nrm[e], n1 = csr_nrm[e+1];
    acc += n0 * xin[(size_t)s0*HD + lane];
    acc += n1 * xin[(size_t)s1*HD + lane];
  }
  if (e < e1) acc += csr_nrm[e] * xin[(size_t)csr_src[e]*HD + lane];
  float v = acc + b1[lane];
  rows[w][lane] = v > 0.f ? v : 0.f;
  __syncthreads();

  float acc2 = 0.f;
  #pragma unroll
  for (int k=0;k<64;++k) acc2 += rows[w][k] * W2s[k*64 + lane];
  x2w[(size_t)i*HD + lane] = acc2;
}

// ---------------- agg2 -> bf16 ----------------
__global__ __launch_bounds__(256) void k_agg2(const float* __restrict__ xin,
                                              const float* __restrict__ b2,
                                              const float* __restrict__ dinv,
                                              const int* __restrict__ rowptr,
                                              const int* __restrict__ csr_src,
                                              const float* __restrict__ csr_nrm,
                                              ushort_t* __restrict__ x2b){
  int lane = threadIdx.x & 63, w = threadIdx.x >> 6;
  int i = blockIdx.x*4 + w;
  float di = dinv[i];
  float acc = di*di * xin[(size_t)i*HD + lane];
  int e = rowptr[i], e1 = rowptr[i+1];
  for (; e + 1 < e1; e += 2){
    int s0 = csr_src[e], s1 = csr_src[e+1];
    float n0 = csr_nrm[e], n1 = csr_nrm[e+1];
    acc += n0 * xin[(size_t)s0*HD + lane];
    acc += n1 * xin[(size_t)s1*HD + lane];
  }
  if (e < e1) acc += csr_nrm[e] * xin[(size_t)csr_src[e]*HD + lane];
  float v = acc + b2[lane];
  v = v > 0.f ? v : 0.f;
  x2b[(size_t)i*HD + lane] = bf16_rne(v);
}

// ---------------- FC + softmax, swapped-operand MFMA ----------------
__global__ __launch_bounds__(256) void k_rowsum(const ushort_t* __restrict__ x2b,
                                                const ushort_t* __restrict__ fcwp,
                                                const float* __restrict__ fcb,
                                                float* __restrict__ S){
  int lane = threadIdx.x & 63, w = threadIdx.x >> 6;
  int r = lane & 15, seg = lane >> 4;
  int row0 = blockIdx.x*128 + w*32;
  const ushort_t* xb = x2b + (size_t)(row0 + r)*HD + seg*8;
  v8s x00 = *(const v8s*)(xb);
  v8s x01 = *(const v8s*)(xb + 32);
  v8s x10 = *(const v8s*)(xb + 16*HD);
  v8s x11 = *(const v8s*)(xb + 16*HD + 32);
  float rp0 = 0.f, rp1 = 0.f;
  for (int cb=0; cb<4; ++cb){
    int colbase = blockIdx.y*256 + cb*64;
    f32x4 z = {0.f,0.f,0.f,0.f};
    f32x4 acc0[4] = {z,z,z,z}, acc1[4] = {z,z,z,z};
    #pragma unroll
    for (int nt=0; nt<4; ++nt){
      int cblk = (colbase >> 4) + nt;
      v8s bA = *(const v8s*)(fcwp + ((size_t)cblk*16 + r)*32 + seg*8);
      v8s bB = *(const v8s*)(fcwp + ((size_t)(512 + cblk)*16 + r)*32 + seg*8);
      acc0[nt] = mfma16(bA, x00, acc0[nt]);
      acc0[nt] = mfma16(bB, x01, acc0[nt]);
      acc1[nt] = mfma16(bA, x10, acc1[nt]);
      acc1[nt] = mfma16(bB, x11, acc1[nt]);
    }
    #pragma unroll
    for (int nt=0; nt<4; ++nt){
      int col = colbase + nt*16 + seg*4;
      f32x4 fb = *(const f32x4*)(fcb + col);
      #pragma unroll
      for (int j=0;j<4;++j){
        rp0 += __expf(acc0[nt][j] + fb[j]);
        rp1 += __expf(acc1[nt][j] + fb[j]);
      }
    }
  }
  rp0 += __shfl_xor(rp0, 16); rp0 += __shfl_xor(rp0, 32);
  rp1 += __shfl_xor(rp1, 16); rp1 += __shfl_xor(rp1, 32);
  if (lane < 16){
    atomicAdd(&S[row0 + lane],      rp0);
    atomicAdd(&S[row0 + 16 + lane], rp1);
  }
}

__global__ __launch_bounds__(256) void k_passB(const ushort_t* __restrict__ x2b,
                                               const ushort_t* __restrict__ fcwp,
                                               const float* __restrict__ fcb,
                                               const float* __restrict__ S,
                                               float* __restrict__ out){
  int lane = threadIdx.x & 63, w = threadIdx.x >> 6;
  int r = lane & 15, seg = lane >> 4;
  int row0 = blockIdx.x*128 + w*32;
  const ushort_t* xb = x2b + (size_t)(row0 + r)*HD + seg*8;
  v8s x00 = *(const v8s*)(xb);
  v8s x01 = *(const v8s*)(xb + 32);
  v8s x10 = *(const v8s*)(xb + 16*HD);
  v8s x11 = *(const v8s*)(xb + 16*HD + 32);
  float si0 = 1.0f / S[row0 + r];
  float si1 = 1.0f / S[row0 + 16 + r];
  float* o0 = out + (size_t)(row0 + r)*NN;
  float* o1 = out + (size_t)(row0 + 16 + r)*NN;
  for (int cb=0; cb<4; ++cb){
    int colbase = blockIdx.y*256 + cb*64;
    f32x4 z = {0.f,0.f,0.f,0.f};
    f32x4 acc0[4] = {z,z,z,z}, acc1[4] = {z,z,z,z};
    #pragma unroll
    for (int nt=0; nt<4; ++nt){
      int cblk = (colbase >> 4) + nt;
      v8s bA = *(const v8s*)(fcwp + ((size_t)cblk*16 + r)*32 + seg*8);
      v8s bB = *(const v8s*)(fcwp + ((size_t)(512 + cblk)*16 + r)*32 + seg*8);
      acc0[nt] = mfma16(bA, x00, acc0[nt]);
      acc0[nt] = mfma16(bB, x01, acc0[nt]);
      acc1[nt] = mfma16(bA, x10, acc1[nt]);
      acc1[nt] = mfma16(bB, x11, acc1[nt]);
    }
    #pragma unroll
    for (int nt=0; nt<4; ++nt){
      int col = colbase + nt*16 + seg*4;
      f32x4 fb = *(const f32x4*)(fcb + col);
      f32x4 v0, v1;
      #pragma unroll
      for (int j=0;j<4;++j){
        v0[j] = __expf(acc0[nt][j] + fb[j]) * si0;
        v1[j] = __expf(acc1[nt][j] + fb[j]) * si1;
      }
      *(f32x4*)(o0 + col) = v0;
      *(f32x4*)(o1 + col) = v1;
    }
  }
}

// ---------------- host ----------------
extern "C" void kernel_launch(void* const* d_in, const int* in_sizes, int n_in,
                              void* d_out, int out_size, void* d_ws, size_t ws_size,
                              hipStream_t stream){
  (void)in_sizes; (void)n_in; (void)out_size; (void)ws_size;
  const int*   ei  = (const int*)  d_in[0];
  const float* ew  = (const float*)d_in[1];
  const float* X   = (const float*)d_in[2];
  const float* W1  = (const float*)d_in[3];
  const float* b1  = (const float*)d_in[4];
  const float* W2  = (const float*)d_in[5];
  const float* b2  = (const float*)d_in[6];
  const float* fcW = (const float*)d_in[7];
  const float* fcb = (const float*)d_in[8];
  float* out = (float*)d_out;
  char*  ws  = (char*)d_ws;

  float*    deg     = (float*)   (ws + 0);
  float*    dinv    = (float*)   (ws + 32768);
  int*      cnt     = (int*)     (ws + 65536);
  int*      wcnt    = (int*)     (ws + 98304);
  int*      rowptr  = (int*)     (ws + 131072);
  int*      csr_src = (int*)     (ws + 167936);
  float*    csr_nrm = (float*)   (ws + 1216512);
  ushort_t* w1hi    = (ushort_t*)(ws + 2265088);
  ushort_t* fcwp    = (ushort_t*)(ws + 4362240);
  float*    xw1p    = (float*)   (ws + 5410816);   // NKC * 2 MB = 16 MB
  float*    xw1     = (float*)   (ws + 22188032);
  float*    x2w     = (float*)   (ws + 24285184);
  ushort_t* x2b     = (ushort_t*)(ws + 26382336);
  float*    S       = (float*)   (ws + 27430912);

  // X bf16 scratch lives in d_out's first 128 MB; gemm1 consumes it long
  // before k_passB overwrites d_out (same stream, serial).
  ushort_t* Xbf = (ushort_t*)d_out;

  k_prep0   <<<2048,  256, 0, stream>>>(W1, fcW, w1hi, fcwp, deg, cnt, wcnt, S);
  k_xcast   <<<32768, 256, 0, stream>>>(X, Xbf);
  k_deg_cnt <<<1024,  256, 0, stream>>>(ei, ew, deg, cnt);
  k_scan    <<<1,     256, 0, stream>>>(cnt, deg, rowptr, dinv);
  k_fill    <<<1024,  256, 0, stream>>>(ei, ew, dinv, rowptr, wcnt, csr_src, csr_nrm);
  k_gemm1   <<<dim3(128, NKC), 256, 0, stream>>>(Xbf, w1hi, xw1p);
  k_red     <<<512,   256, 0, stream>>>(xw1p, xw1);
  k_agg1c   <<<2048,  256, 0, stream>>>(xw1, b1, W2, dinv, rowptr, csr_src, csr_nrm, x2w);
  k_agg2    <<<2048,  256, 0, stream>>>(x2w, b2, dinv, rowptr, csr_src, csr_nrm, x2b);
  k_rowsum  <<<dim3(64,32), 256, 0, stream>>>(x2b, fcwp, fcb, S);
  k_passB   <<<dim3(64,32), 256, 0, stream>>>(x2b, fcwp, fcb, S, out);
}